// Round 6
// baseline (901.066 us; speedup 1.0000x reference)
//
#include <hip/hip_runtime.h>

#define HN  128
#define NPG 32
#define HK  64          // half feature width resident in LDS
#define SXH 68          // padded row stride (floats) for half tiles
#define NT  512
#define NW  8           // waves per block; 1 wave == 1 graph
#define SPG 16          // graphs per wave

typedef float f4 __attribute__((ext_vector_type(4)));
typedef float f2 __attribute__((ext_vector_type(2)));

__global__ __launch_bounds__(NT) void gib_main(
    const float* __restrict__ x,  const float* __restrict__ W1,
    const float* __restrict__ b1, const float* __restrict__ W2,
    const float* __restrict__ b2, const float* __restrict__ gn,
    const float* __restrict__ un, const int* __restrict__ ei,
    float* __restrict__ out, float* __restrict__ ws,
    int G, long E, int epg)
{
  const int t  = threadIdx.x;
  const int wv = t >> 6;
  const int l  = t & 63;
  const int ng = l & 3;    // MLP: nodes ng,ng+4,...,ng+28
  const int cg = l >> 2;   // MLP: cols 8cg..8cg+7
  const int cp = l & 31;   // stats/T2: col-pair 2cp within half
  const int nh = l >> 5;   // stats/T2: node half

  __shared__ __align__(16) float W1s[HN * HN];
  __shared__ __align__(16) float xs[NW][NPG * SXH];
  __shared__ float s_mean[NW][HN], s_std[NW][HN], s_iv[NW][HN];
  __shared__ float s_lp[NW][NPG], s_a0[NW][NPG];

  const long GL = (long)G * HN;

  // ---- stage W1 once, column-chunk de-interleaved (slot trick from r5) ----
  #pragma unroll
  for (int r = 0; r < 8; ++r) {
    int s = r * NT + t;
    int k = s >> 5, gm = s & 31;
    int slot = ((gm & 1) << 4) | (gm >> 1);
    *(f4*)&W1s[k * HN + slot * 4] = *(const f4*)(W1 + s * 4);
  }
  __syncthreads();   // the only block-wide barrier

  float* xh = &xs[wv][0];

  const f4 b1A = *(const f4*)(b1 + 8 * cg);
  const f4 b1B = *(const f4*)(b1 + 8 * cg + 4);
  f4 w2q[4];   // W2 rows 8cg..8cg+7, pairs interleaved
  #pragma unroll
  for (int u = 0; u < 4; ++u) w2q[u] = *(const f4*)(W2 + 16 * cg + 4 * u);
  const float b20 = b2[0], b21 = b2[1];

  const long gbase = ((long)blockIdx.x * NW + wv) * SPG;
  const int sr = l >> 4, sc = l & 15;   // staging: rows sr+8i, col-chunk sc

  // pre-stage h0 of first graph (wave-local)
  {
    const float* xg = x + gbase * NPG * HN;
    #pragma unroll
    for (int r = 0; r < 8; ++r) {
      int n = r + 8 * sr;
      f4 v = *(const f4*)(xg + n * HN + sc * 4);
      *(f4*)&xh[n * SXH + sc * 4] = v;
    }
  }

  for (int si = 0; si < SPG; ++si) {
    const long g = gbase + si;
    if (g >= G) break;
    const long nb = g * NPG;
    const float* xg = x + nb * HN;

    // ---- prefetch h1 + gn ----
    f4 Lh[8];
    #pragma unroll
    for (int r = 0; r < 8; ++r)
      Lh[r] = *(const f4*)(xg + (r + 8 * sr) * HN + HK + sc * 4);
    f2 gnr[8];
    if (l < 4) {
      #pragma unroll
      for (int i = 0; i < 8; ++i)
        gnr[i] = *(const f2*)(gn + (nb + l + 4 * i) * 2);
    }

    // ---- stats partial h0 ----
    f2 s1h0 = {0.f, 0.f}, sqh0 = {0.f, 0.f};
    #pragma unroll
    for (int i = 0; i < 16; ++i) {
      f2 v = *(const f2*)&xh[(nh * 16 + i) * SXH + 2 * cp];
      s1h0[0] += v[0]; s1h0[1] += v[1];
      sqh0[0] = fmaf(v[0], v[0], sqh0[0]);
      sqh0[1] = fmaf(v[1], v[1], sqh0[1]);
    }

    // ---- MLP phase 0 (k 0..63) ----
    f4 accA[8], accB[8];
    #pragma unroll
    for (int i = 0; i < 8; ++i) { accA[i] = b1A; accB[i] = b1B; }
    #pragma unroll 4
    for (int kc = 0; kc < 16; ++kc) {
      const int kr = kc * 4;
      f4 wA0 = *(const f4*)&W1s[(kr + 0) * HN + cg * 4];
      f4 wA1 = *(const f4*)&W1s[(kr + 1) * HN + cg * 4];
      f4 wA2 = *(const f4*)&W1s[(kr + 2) * HN + cg * 4];
      f4 wA3 = *(const f4*)&W1s[(kr + 3) * HN + cg * 4];
      f4 wB0 = *(const f4*)&W1s[(kr + 0) * HN + 64 + cg * 4];
      f4 wB1 = *(const f4*)&W1s[(kr + 1) * HN + 64 + cg * 4];
      f4 wB2 = *(const f4*)&W1s[(kr + 2) * HN + 64 + cg * 4];
      f4 wB3 = *(const f4*)&W1s[(kr + 3) * HN + 64 + cg * 4];
      #pragma unroll
      for (int i = 0; i < 8; ++i) {
        f4 xv = *(const f4*)&xh[(ng + 4 * i) * SXH + kc * 4];
        accA[i] += wA0 * xv[0]; accB[i] += wB0 * xv[0];
        accA[i] += wA1 * xv[1]; accB[i] += wB1 * xv[1];
        accA[i] += wA2 * xv[2]; accB[i] += wB2 * xv[2];
        accA[i] += wA3 * xv[3]; accB[i] += wB3 * xv[3];
      }
    }

    // ---- write h1 tile; re-issue h0 loads; prefetch edges ----
    #pragma unroll
    for (int r = 0; r < 8; ++r)
      *(f4*)&xh[(r + 8 * sr) * SXH + sc * 4] = Lh[r];
    f4 Lh2[8];
    #pragma unroll
    for (int r = 0; r < 8; ++r)
      Lh2[r] = *(const f4*)(xg + (r + 8 * sr) * HN + sc * 4);
    int es0 = 0, ed0 = 0, es1 = 0, ed1 = 0;
    if (l < epg)      { es0 = ei[g * epg + l];      ed0 = ei[E + g * epg + l]; }
    if (l + 64 < epg) { es1 = ei[g * epg + l + 64]; ed1 = ei[E + g * epg + l + 64]; }

    // ---- stats partial h1 ----
    f2 s1h1 = {0.f, 0.f}, sqh1 = {0.f, 0.f};
    #pragma unroll
    for (int i = 0; i < 16; ++i) {
      f2 v = *(const f2*)&xh[(nh * 16 + i) * SXH + 2 * cp];
      s1h1[0] += v[0]; s1h1[1] += v[1];
      sqh1[0] = fmaf(v[0], v[0], sqh1[0]);
      sqh1[1] = fmaf(v[1], v[1], sqh1[1]);
    }

    // ---- MLP phase 1 (k 64..127) ----
    #pragma unroll 4
    for (int kc = 0; kc < 16; ++kc) {
      const int kr = (HK + kc * 4);
      f4 wA0 = *(const f4*)&W1s[(kr + 0) * HN + cg * 4];
      f4 wA1 = *(const f4*)&W1s[(kr + 1) * HN + cg * 4];
      f4 wA2 = *(const f4*)&W1s[(kr + 2) * HN + cg * 4];
      f4 wA3 = *(const f4*)&W1s[(kr + 3) * HN + cg * 4];
      f4 wB0 = *(const f4*)&W1s[(kr + 0) * HN + 64 + cg * 4];
      f4 wB1 = *(const f4*)&W1s[(kr + 1) * HN + 64 + cg * 4];
      f4 wB2 = *(const f4*)&W1s[(kr + 2) * HN + 64 + cg * 4];
      f4 wB3 = *(const f4*)&W1s[(kr + 3) * HN + 64 + cg * 4];
      #pragma unroll
      for (int i = 0; i < 8; ++i) {
        f4 xv = *(const f4*)&xh[(ng + 4 * i) * SXH + kc * 4];
        accA[i] += wA0 * xv[0]; accB[i] += wB0 * xv[0];
        accA[i] += wA1 * xv[1]; accB[i] += wB1 * xv[1];
        accA[i] += wA2 * xv[2]; accB[i] += wB2 * xv[2];
        accA[i] += wA3 * xv[3]; accB[i] += wB3 * xv[3];
      }
    }

    // ---- stats finalize (both halves) ----
    float r2acc = 0.f;
    {
      #pragma unroll
      for (int h = 0; h < 2; ++h) {
        f2 s1 = h ? s1h1 : s1h0, sq = h ? sqh1 : sqh0;
        float a0s = s1[0] + __shfl_xor(s1[0], 32, 64);
        float a1s = s1[1] + __shfl_xor(s1[1], 32, 64);
        float q0s = sq[0] + __shfl_xor(sq[0], 32, 64);
        float q1s = sq[1] + __shfl_xor(sq[1], 32, 64);
        float m0 = a0s * (1.f / NPG), m1 = a1s * (1.f / NPG);
        float v0 = fmaxf((q0s - a0s * m0) * (1.f / (NPG - 1)), 0.f);
        float v1 = fmaxf((q1s - a1s * m1) * (1.f / (NPG - 1)), 0.f);
        float sd0 = sqrtf(v0), sd1 = sqrtf(v1);
        float in0 = 1.f / (sd0 + 1e-7f), in1 = 1.f / (sd1 + 1e-7f);
        if (l < 32) {
          f2 mv = {m0, m1}, sv = {sd0, sd1}, iv = {in0 * in0, in1 * in1};
          *(f2*)&s_mean[wv][h * HK + 2 * cp] = mv;
          *(f2*)&s_std [wv][h * HK + 2 * cp] = sv;
          *(f2*)&s_iv  [wv][h * HK + 2 * cp] = iv;
          f2 ge = {a0s, a1s};
          *(f2*)&out[g * HN + h * HK + 2 * cp] = ge;     // graph_emb
        }
        float r0 = sd0 * in0, r1 = sd1 * in1;
        r2acc += r0 * r0 + r1 * r1;
      }
      #pragma unroll
      for (int m = 1; m <= 16; m <<= 1) r2acc += __shfl_xor(r2acc, m, 64);
      // lane 0 now holds sr2
    }

    // ---- z epilogue: tanh + W2 + in-wave reduce ----
    float zz0[8], zz1[8];
    #pragma unroll
    for (int i = 0; i < 8; ++i) {
      float h0 = tanhf(accA[i][0]), h1 = tanhf(accA[i][1]);
      float h2 = tanhf(accA[i][2]), h3 = tanhf(accA[i][3]);
      float h4 = tanhf(accB[i][0]), h5 = tanhf(accB[i][1]);
      float h6 = tanhf(accB[i][2]), h7 = tanhf(accB[i][3]);
      float z0 = h0 * w2q[0][0] + h1 * w2q[0][2] + h2 * w2q[1][0] + h3 * w2q[1][2]
               + h4 * w2q[2][0] + h5 * w2q[2][2] + h6 * w2q[3][0] + h7 * w2q[3][2];
      float z1 = h0 * w2q[0][1] + h1 * w2q[0][3] + h2 * w2q[1][1] + h3 * w2q[1][3]
               + h4 * w2q[2][1] + h5 * w2q[2][3] + h6 * w2q[3][1] + h7 * w2q[3][3];
      #pragma unroll
      for (int m = 4; m <= 32; m <<= 1) {
        z0 += __shfl_xor(z0, m, 64);
        z1 += __shfl_xor(z1, m, 64);
      }
      zz0[i] = z0; zz1[i] = z1;
    }

    // ---- softmax + gumbel (lanes 0..3, 8 nodes each) ----
    float vSLN = 0.f, vSLN2 = 0.f, vpres = 0.f;
    if (l < 4) {
      #pragma unroll
      for (int i = 0; i < 8; ++i) {
        const int n = l + 4 * i;
        float z0 = b20 + zz0[i], z1 = b21 + zz1[i];
        float zm = fmaxf(z0, z1);
        float e0 = expf(z0 - zm), e1 = expf(z1 - zm);
        float a0 = e0 / (e0 + e1), a1 = 1.f - a0;
        float q0 = a0 + gnr[i][0], q1 = a1 + gnr[i][1];
        float qm = fmaxf(q0, q1);
        float E0 = expf(q0 - qm), E1 = expf(q1 - qm);
        float lp = E0 / (E0 + E1), ln = 1.f - lp;
        s_lp[wv][n] = lp; s_a0[wv][n] = a0;
        out[2 * GL + nb + n] = (lp > 0.5f) ? 1.0f : 0.0f;   // active
        vSLN += ln; vSLN2 += ln * ln; vpres += (a0 > 0.5f) ? 1.f : 0.f;
      }
      vSLN  += __shfl_xor(vSLN, 1, 64);  vSLN  += __shfl_xor(vSLN, 2, 64);
      vSLN2 += __shfl_xor(vSLN2, 1, 64); vSLN2 += __shfl_xor(vSLN2, 2, 64);
      vpres += __shfl_xor(vpres, 1, 64); vpres += __shfl_xor(vpres, 2, 64);
    }
    const float SLN = __shfl(vSLN, 0, 64);

    // ---- T2 + noisy, h=1 (resident), then restage h0, then h=0 ----
    float tv = 0.f;
    {
      // h = 1
      f2 ur[16];
      #pragma unroll
      for (int i = 0; i < 16; ++i)
        ur[i] = *(const f2*)(un + (nb + nh * 16 + i) * HN + HK + 2 * cp);
      f2 mu = *(const f2*)&s_mean[wv][HK + 2 * cp];
      f2 iv = *(const f2*)&s_iv [wv][HK + 2 * cp];
      float A0 = 0.f, A1 = 0.f, B0 = 0.f, B1 = 0.f;
      #pragma unroll
      for (int i = 0; i < 16; ++i) {
        const int n = nh * 16 + i;
        f2 v = *(const f2*)&xh[n * SXH + 2 * cp];
        float lpn = s_lp[wv][n], lnn = 1.f - lpn;
        float d0 = v[0] - mu[0], d1 = v[1] - mu[1];
        tv = fmaf(lpn * lpn, fmaf(d0 * d0, iv[0], d1 * d1 * iv[1]), tv);
        A0 = fmaf(lpn, v[0], A0); A1 = fmaf(lpn, v[1], A1);
        B0 = fmaf(lnn, ur[i][0], B0); B1 = fmaf(lnn, ur[i][1], B1);
      }
      A0 += __shfl_xor(A0, 32, 64); A1 += __shfl_xor(A1, 32, 64);
      B0 += __shfl_xor(B0, 32, 64); B1 += __shfl_xor(B1, 32, 64);
      if (l < 32) {
        f2 sd = *(const f2*)&s_std[wv][HK + 2 * cp];
        f2 ne = {fmaf(mu[0], SLN, A0) + sd[0] * B0,
                 fmaf(mu[1], SLN, A1) + sd[1] * B1};
        *(f2*)&out[GL + g * HN + HK + 2 * cp] = ne;   // noisy_emb high half
      }
    }

    // ---- edges -> 2x2 adjacency ----
    float c00 = 0.f, c01 = 0.f, c10 = 0.f, c11 = 0.f;
    {
      if (l < epg) {
        int s2 = es0 - (int)nb, d2 = ed0 - (int)nb;
        float as0 = s_a0[wv][s2], as1 = 1.f - as0;
        float ad0 = s_a0[wv][d2], ad1 = 1.f - ad0;
        c00 = as0 * ad0; c01 = as0 * ad1; c10 = as1 * ad0; c11 = as1 * ad1;
      }
      if (l + 64 < epg) {
        int s2 = es1 - (int)nb, d2 = ed1 - (int)nb;
        float as0 = s_a0[wv][s2], as1 = 1.f - as0;
        float ad0 = s_a0[wv][d2], ad1 = 1.f - ad0;
        c00 = fmaf(as0, ad0, c00); c01 = fmaf(as0, ad1, c01);
        c10 = fmaf(as1, ad0, c10); c11 = fmaf(as1, ad1, c11);
      }
      for (int e = 128 + l; e < epg; e += 64) {
        int s2 = ei[g * epg + e] - (int)nb, d2 = ei[E + g * epg + e] - (int)nb;
        float as0 = s_a0[wv][s2], as1 = 1.f - as0;
        float ad0 = s_a0[wv][d2], ad1 = 1.f - ad0;
        c00 = fmaf(as0, ad0, c00); c01 = fmaf(as0, ad1, c01);
        c10 = fmaf(as1, ad0, c10); c11 = fmaf(as1, ad1, c11);
      }
      #pragma unroll
      for (int m = 1; m <= 32; m <<= 1) {
        c00 += __shfl_xor(c00, m, 64); c01 += __shfl_xor(c01, m, 64);
        c10 += __shfl_xor(c10, m, 64); c11 += __shfl_xor(c11, m, 64);
      }
    }

    // ---- restage h0; prefetch next graph's h0 ----
    #pragma unroll
    for (int r = 0; r < 8; ++r)
      *(f4*)&xh[(r + 8 * sr) * SXH + sc * 4] = Lh2[r];
    const long gnx = (g + 1 < G) ? (g + 1) : g;
    f4 Lh3[8];
    #pragma unroll
    for (int r = 0; r < 8; ++r)
      Lh3[r] = *(const f4*)(x + (gnx * NPG + r + 8 * sr) * HN + sc * 4);

    {
      // h = 0
      f2 ur[16];
      #pragma unroll
      for (int i = 0; i < 16; ++i)
        ur[i] = *(const f2*)(un + (nb + nh * 16 + i) * HN + 2 * cp);
      f2 mu = *(const f2*)&s_mean[wv][2 * cp];
      f2 iv = *(const f2*)&s_iv [wv][2 * cp];
      float A0 = 0.f, A1 = 0.f, B0 = 0.f, B1 = 0.f;
      #pragma unroll
      for (int i = 0; i < 16; ++i) {
        const int n = nh * 16 + i;
        f2 v = *(const f2*)&xh[n * SXH + 2 * cp];
        float lpn = s_lp[wv][n], lnn = 1.f - lpn;
        float d0 = v[0] - mu[0], d1 = v[1] - mu[1];
        tv = fmaf(lpn * lpn, fmaf(d0 * d0, iv[0], d1 * d1 * iv[1]), tv);
        A0 = fmaf(lpn, v[0], A0); A1 = fmaf(lpn, v[1], A1);
        B0 = fmaf(lnn, ur[i][0], B0); B1 = fmaf(lnn, ur[i][1], B1);
      }
      A0 += __shfl_xor(A0, 32, 64); A1 += __shfl_xor(A1, 32, 64);
      B0 += __shfl_xor(B0, 32, 64); B1 += __shfl_xor(B1, 32, 64);
      if (l < 32) {
        f2 sd = *(const f2*)&s_std[wv][2 * cp];
        f2 ne = {fmaf(mu[0], SLN, A0) + sd[0] * B0,
                 fmaf(mu[1], SLN, A1) + sd[1] * B1};
        *(f2*)&out[GL + g * HN + 2 * cp] = ne;        // noisy_emb low half
      }
    }
    #pragma unroll
    for (int m = 1; m <= 32; m <<= 1) tv += __shfl_xor(tv, m, 64);

    if (l == 0) {
      float d0 = c00 / fmaxf(fabsf(c00) + fabsf(c01), 1e-12f);
      float d1 = c11 / fmaxf(fabsf(c10) + fabsf(c11), 1e-12f);
      float pen = 0.5f * ((d0 - 1.f) * (d0 - 1.f) + (d1 - 1.f) * (d1 - 1.f));
      float kl = (0.5f * vSLN2 * r2acc + (float)NPG * tv) / (float)(NPG * HN);
      ws[g]                 = kl;
      ws[(size_t)G + g]     = pen;
      ws[2 * (size_t)G + g] = vpres * (1.0f / NPG);
    }

    // ---- stage next graph's h0 tile ----
    #pragma unroll
    for (int r = 0; r < 8; ++r)
      *(f4*)&xh[(r + 8 * sr) * SXH + sc * 4] = Lh3[r];
  }
}

// deterministic fixed-order reduction of the 3 per-graph scalar arrays
__global__ __launch_bounds__(1024) void gib_final(const float* __restrict__ ws,
                                                  float* __restrict__ out,
                                                  int G, long base)
{
  __shared__ float red[3][16];
  const int t = threadIdx.x, w = t >> 6, lid = t & 63;
  float s0 = 0.f, s1 = 0.f, s2 = 0.f;
  for (int i = t; i < G; i += 1024) {
    s0 += ws[(size_t)G + i];       // pos_penalty
    s1 += ws[i];                   // kl
    s2 += ws[2 * (size_t)G + i];   // preserve
  }
  #pragma unroll
  for (int m = 1; m <= 32; m <<= 1) {
    s0 += __shfl_xor(s0, m, 64);
    s1 += __shfl_xor(s1, m, 64);
    s2 += __shfl_xor(s2, m, 64);
  }
  if (lid == 0) { red[0][w] = s0; red[1][w] = s1; red[2][w] = s2; }
  __syncthreads();
  if (t == 0) {
    float r0 = 0.f, r1 = 0.f, r2 = 0.f;
    for (int i = 0; i < 16; ++i) { r0 += red[0][i]; r1 += red[1][i]; r2 += red[2][i]; }
    out[base + 0] = r0 / (float)G;
    out[base + 1] = r1 / (float)G;
    out[base + 2] = r2 / (float)G;
  }
}

extern "C" void kernel_launch(void* const* d_in, const int* in_sizes, int n_in,
                              void* d_out, int out_size, void* d_ws, size_t ws_size,
                              hipStream_t stream)
{
  const float* x  = (const float*)d_in[0];
  const float* W1 = (const float*)d_in[1];
  const float* b1 = (const float*)d_in[2];
  const float* W2 = (const float*)d_in[3];
  const float* b2 = (const float*)d_in[4];
  const float* gn = (const float*)d_in[5];
  const float* un = (const float*)d_in[6];
  const int*   ei = (const int*)d_in[7];
  float* out = (float*)d_out;
  float* ws  = (float*)d_ws;

  const long N = (long)in_sizes[0] / HN;
  const int  G = (int)(N / NPG);
  const long E = (long)in_sizes[7] / 2;
  const int epg = (int)(E / G);

  const int nblocks = (G + NW * SPG - 1) / (NW * SPG);   // 32768/128 = 256
  hipLaunchKernelGGL(gib_main, dim3(nblocks), dim3(NT), 0, stream,
                     x, W1, b1, W2, b2, gn, un, ei, out, ws, G, E, epg);
  const long base = 2L * (long)G * HN + N;
  hipLaunchKernelGGL(gib_final, dim3(1), dim3(1024), 0, stream, ws, out, G, base);
}